// Round 18
// baseline (1268.992 us; speedup 1.0000x reference)
//
#include <hip/hip_runtime.h>
#include <math.h>

#define T_LEN 32768
#define NLAYERS 30
#define NBLK 512
#define SQRT_HALF 0.70710678118654752f
#define C30 0.18257418583505537f

typedef short short8 __attribute__((ext_vector_type(8)));
typedef short short4v __attribute__((ext_vector_type(4)));
typedef float float4v __attribute__((ext_vector_type(4)));
typedef unsigned short u16;
typedef unsigned long long u64t;
typedef u64t u64x2 __attribute__((ext_vector_type(2)));

__device__ inline u16 rne_bf16(float f){
    unsigned u = __builtin_bit_cast(unsigned, f);
    u += 0x7fffu + ((u >> 16) & 1u);
    return (u16)(u >> 16);
}
__device__ inline float bf16_to_f32(u16 h){
    unsigned u = ((unsigned)h) << 16;
    return __builtin_bit_cast(float, u);
}
__device__ inline void split_bf16(float f, u16& hi, u16& lo){
    hi = rne_bf16(f);
    float r = f - bf16_to_f32(hi);
    lo = rne_bf16(r);
}

// system-scope (sc0 sc1) accesses for cross-XCD mirror buffers
__device__ inline u64t ld_sys(const u16* p){
    return __hip_atomic_load((const u64t*)p, __ATOMIC_RELAXED, __HIP_MEMORY_SCOPE_SYSTEM);
}
__device__ inline void st_sys(u16* p, u64t v){
    __hip_atomic_store((u64t*)p, v, __ATOMIC_RELAXED, __HIP_MEMORY_SCOPE_SYSTEM);
}
__device__ inline unsigned ld_sys32(const unsigned* p){
    return __hip_atomic_load(p, __ATOMIC_RELAXED, __HIP_MEMORY_SCOPE_SYSTEM);
}
__device__ inline void st_sys32(unsigned* p, unsigned v){
    __hip_atomic_store(p, v, __ATOMIC_RELAXED, __HIP_MEMORY_SCOPE_SYSTEM);
}
__device__ inline unsigned ld_ag(const unsigned* p){
    return __hip_atomic_load(p, __ATOMIC_RELAXED, __HIP_MEMORY_SCOPE_AGENT);
}
__device__ inline void st_ag(unsigned* p, unsigned v){
    __hip_atomic_store(p, v, __ATOMIC_RELAXED, __HIP_MEMORY_SCOPE_AGENT);
}

// ---------------- weight prep: single-plane bf16 chunks (8KB each) ----------------
__global__ void prep_wmain(const float* __restrict__ Wd, const float* __restrict__ Wa,
                           u16* __restrict__ WA)
{
    int idx = blockIdx.x * 256 + threadIdx.x;
    if (idx >= NLAYERS * 9 * 8 * 64) return;
    int lane = idx & 63;
    int mb = (idx >> 6) & 7;
    int cc = (idx >> 9) % 9;
    int l_ = (idx >> 9) / 9;
    int m = mb * 16 + (lane & 15);
    int kbase = cc * 32 + (lane >> 4) * 8;
    size_t base = ((size_t)(l_ * 9 + cc)) * 4096 + mb * 512 + lane * 8;
#pragma unroll
    for (int j = 0; j < 8; ++j) {
        int k = kbase + j;
        float v = 0.f;
        if (k < 192) {
            int tap = k >> 6, i = k & 63;
            v = Wd[((size_t)(l_ * 128 + m) * 64 + i) * 3 + tap];
        } else if (k < 272) {
            v = Wa[(size_t)(l_ * 128 + m) * 80 + (k - 192)];
        }
        WA[base + j] = rne_bf16(v);
    }
}

__global__ void prep_wsr(const float* __restrict__ Ws, const float* __restrict__ Wr,
                         u16* __restrict__ W2)
{
    int idx = blockIdx.x * 256 + threadIdx.x;
    if (idx >= NLAYERS * 2 * 8 * 64) return;
    int lane = idx & 63;
    int mb = (idx >> 6) & 7;
    int cc = (idx >> 9) & 1;
    int l_ = idx >> 10;
    int m2 = mb * 16 + (lane & 15);
    int kbase = cc * 32 + (lane >> 4) * 8;
    size_t base = ((size_t)(l_ * 2 + cc)) * 4096 + mb * 512 + lane * 8;
#pragma unroll
    for (int j = 0; j < 8; ++j) {
        int k2 = kbase + j;
        float v = (m2 < 64) ? Ws[(size_t)(l_ * 64 + m2) * 64 + k2]
                            : Wr[(size_t)(l_ * 64 + (m2 - 64)) * 64 + k2];
        W2[base + j] = rne_bf16(v);
    }
}

// ---------------- upsampler (t-major) ----------------
__global__ void cin_kernel(const float* __restrict__ c, const float* __restrict__ Wcin,
                           float* __restrict__ c1)
{
    int idx = blockIdx.x * 256 + threadIdx.x;
    if (idx >= 2 * 128 * 80) return;
    int o = idx % 80;
    int f = (idx / 80) & 127;
    int b = idx / (80 * 128);
    float acc = 0.f;
    for (int ch = 0; ch < 80; ++ch)
        acc = fmaf(Wcin[o * 80 + ch], c[(b * 80 + ch) * 128 + f], acc);
    c1[idx] = acc;
}

__global__ void up_kernel(const float* __restrict__ in, float* __restrict__ out,
                          const float* __restrict__ w9, int Win)
{
    int idx = blockIdx.x * 256 + threadIdx.x;
    int Wout = Win * 4;
    int total = 2 * Wout * 80;
    if (idx >= total) return;
    int a = idx % 80;
    int t = (idx / 80) % Wout;
    int b = idx / (80 * Wout);
    const float* ip = in + (size_t)b * Win * 80 + a;
    float acc = 0.f;
#pragma unroll
    for (int j = 0; j < 9; ++j) {
        int q = t + j - 4;
        if (q >= 0 && q < Wout) acc = fmaf(w9[j], ip[(size_t)(q >> 2) * 80], acc);
    }
    out[idx] = acc;
}

__global__ void upfinal_kernel(const float* __restrict__ u3, const float* __restrict__ w9,
                               u16* __restrict__ cup)
{
    int idx = blockIdx.x * 256 + threadIdx.x;
    if (idx >= 2 * T_LEN * 96) return;
    int a = idx % 96;
    int t = (idx / 96) & (T_LEN - 1);
    int b = idx / (96 * T_LEN);
    float acc = 0.f;
    if (a < 80) {
        const float* ip = u3 + (size_t)b * 8192 * 80 + a;
#pragma unroll
        for (int j = 0; j < 9; ++j) {
            int q = t + j - 4;
            if (q >= 0 && q < T_LEN) acc = fmaf(w9[j], ip[(size_t)(q >> 2) * 80], acc);
        }
    }
    cup[idx] = rne_bf16(acc);
}

__global__ void bar_init(unsigned* bar){
    int i = blockIdx.x * 256 + threadIdx.x;
    for (int e = i; e < 33792; e += 256 * 64) bar[e] = 0u;
}

// ---------------- persistent fused WaveNet (32 waves/CU) ----------------
// 512 blocks x 1024 threads; wave tile 64ch x 16t (chw = w&1, tg = w>>1);
// gating via one LDS g-exchange (bf16, XOR-swizzled); z stays in registers.
__global__ __launch_bounds__(1024, 8) void wavenet_kernel(
    const float* __restrict__ x, const float* __restrict__ Wf, const float* __restrict__ bf,
    u16* __restrict__ h0, u16* __restrict__ h1,
    u16* __restrict__ m0, u16* __restrict__ m1,
    const u16* __restrict__ cup,
    const u16* __restrict__ WA_all, const u16* __restrict__ W2_all,
    const float* __restrict__ bd_all, const float* __restrict__ bs_all,
    const float* __restrict__ br_all,
    const float* __restrict__ Wl1, const float* __restrict__ bl1,
    const float* __restrict__ Wl2, const float* __restrict__ bl2,
    float* __restrict__ y, unsigned* __restrict__ bar, unsigned* __restrict__ xcdmap)
{
    __shared__ u16 wa_sm[36864];                // 72 KB: 9 chunks x 8KB (g zones + head alias 0-3)
    const int tid = threadIdx.x;
    const int l  = tid & 63;
    const int w  = tid >> 6;                    // 0..15
    const int chw = w & 1;                      // ch half: 0 -> ch 0..63, 1 -> 64..127
    const int tg  = w >> 1;                     // t-group 0..7
    const int lr = l & 15;
    const int lg = l >> 4;
    const int bx = blockIdx.x;
    const int g  = ((bx & 7) << 6) | (bx >> 3);
    const int b  = g >> 8;
    const int gt = g & 255;
    const int t0blk = gt * 128;
    const int n0 = t0blk + tg * 16;
    char* zg = (char*)wa_sm + tg * 4096;        // g-exchange zone (after post-GEMM sync)

    unsigned* flagP = bar + 1024;
    unsigned* rdP   = bar + 1024 + 16384;

    int dil_cur = 1;

    auto grid_bar = [&](int k){
        __syncthreads();
        if (tid == 0) {
            const unsigned epoch = (unsigned)(k + 1);
            const int grp = bx & 7;
            unsigned* arr  = bar + grp * 32;
            unsigned* root = bar + 8 * 32;
            unsigned* rel  = bar + 9 * 32 + grp * 32;
            unsigned old = __hip_atomic_fetch_add(arr, 1u, __ATOMIC_RELAXED, __HIP_MEMORY_SCOPE_AGENT);
            if (old == epoch * 64u - 1u) {
                unsigned ro = __hip_atomic_fetch_add(root, 1u, __ATOMIC_RELAXED, __HIP_MEMORY_SCOPE_AGENT);
                if (ro == epoch * 8u - 1u) {
#pragma unroll
                    for (int j = 0; j < 8; ++j)
                        __hip_atomic_store(bar + 9 * 32 + j * 32, epoch, __ATOMIC_RELAXED, __HIP_MEMORY_SCOPE_AGENT);
                }
            }
            while (__hip_atomic_load(rel, __ATOMIC_RELAXED, __HIP_MEMORY_SCOPE_AGENT) < epoch)
                __builtin_amdgcn_s_sleep(16);
        }
        __syncthreads();
        asm volatile("buffer_inv" ::: "memory");
    };

    auto wait_nb = [&](const unsigned* fl, unsigned tgt){
        if (tid < 9 && tid != 4) {
            int jt = gt - 4 + tid;
            if (jt >= 0 && jt < 256) {
                const unsigned* fp = fl + (size_t)(b * 256 + jt) * 32;
                while (ld_ag(fp) < tgt) __builtin_amdgcn_s_sleep(4);
            }
        }
        __syncthreads();
    };

    auto wld = [&](const u16* Wg, int c){ return *(const short4v*)(Wg + (size_t)c * 4096 + tid * 4); };
    auto wst = [&](int c, short4v v){ *(short4v*)((char*)wa_sm + c * 8192 + tid * 8) = v; };

    // ---- publish tile->XCD map, build foreign mask
    unsigned myxcd;
    asm volatile("s_getreg_b32 %0, hwreg(HW_REG_XCC_ID)" : "=s"(myxcd));
    if (tid == 0) st_sys32(xcdmap + g, myxcd);
    grid_bar(0);

    unsigned fmask = 0;
    for (int i = 0; i < 11; ++i) {
        int j = gt - 5 + i;
        if (i != 5 && j >= 0 && j < 256) {
            unsigned xv = ld_sys32(xcdmap + b * 256 + j);
            if (xv != myxcd) fmask |= 1u << i;
        }
    }
    int lkT = -1000000, rkT = 1000000;
    for (int i = 4; i >= 0; --i) if ((fmask >> i) & 1) { lkT = t0blk + 128 * (i - 4) - 1; break; }
    for (int i = 6; i <= 10; ++i) if ((fmask >> i) & 1) { rkT = t0blk + 128 * (i - 5); break; }

    u16* hih = h0;
    u16* hoh = h1;
    u16* mih = m0;
    u16* moh = m1;
    const short8 zero8 = (short8)0;

    auto issue_bfrag = [&](int cc, short8& BH){
        if (cc < 6) {
            const int tap = cc >> 1;
            const int i0 = (cc & 1) * 32 + lg * 8;
            const int offd = (tap - 1) * dil_cur;
            int ws0 = n0 + offd;
            int a0 = ws0 < 0 ? 0 : ws0;
            int a1 = (ws0 + 15 >= T_LEN) ? (T_LEN - 1) : (ws0 + 15);
            bool mir = false;
            if (a0 <= a1) {
                int i_0 = (a0 >> 7) - gt + 5;
                int i_1 = (a1 >> 7) - gt + 5;
                mir = ((fmask >> i_0) & 1) || ((fmask >> i_1) & 1);
            }
            int t = n0 + lr + offd;
            if ((unsigned)t < (unsigned)T_LEN) {
                size_t off = ((size_t)b * T_LEN + t) * 64 + i0;
                if (mir) {
                    u64x2 qh;
                    qh.x = ld_sys(mih + off); qh.y = ld_sys(mih + off + 4);
                    BH = __builtin_bit_cast(short8, qh);
                } else {
                    BH = *(const short8*)(hih + off);
                }
            } else { BH = zero8; }
        } else {
            const int a0 = (cc - 6) * 32 + lg * 8;
            int t = n0 + lr;
            BH = *(const short8*)(cup + ((size_t)b * T_LEN + t) * 96 + a0);
        }
    };

    // ---- fused first conv (single-plane h + hi mirror, thr = d0+32 = 33)
#pragma unroll
    for (int e = 0; e < 2; ++e) {
        int q = e * 1024 + tid;
        int tl = q >> 4, ch0 = (q & 15) * 4;
        int t = t0blk + tl;
        size_t bt = (size_t)b * T_LEN + t;
        float xv = x[bt];
        short4v hv4;
#pragma unroll
        for (int r = 0; r < 4; ++r) {
            float v = fmaf(Wf[ch0 + r], xv, bf[ch0 + r]);
            hv4[r] = (short)rne_bf16(v);
        }
        *(short4v*)(h0 + bt * 64 + ch0) = hv4;
        if ((t - lkT <= 33) || (rkT - t <= 33))
            st_sys(m0 + bt * 64 + ch0, __builtin_bit_cast(u64t, hv4));
    }

    float4v skipacc[4];
#pragma unroll
    for (int mb = 0; mb < 4; ++mb) skipacc[mb] = (float4v)0.f;

    __syncthreads();
    if (tid == 0) st_ag(flagP + (size_t)g * 32, 1u);

    // stage layer-0 weights
    {
        short4v r0 = wld(WA_all, 0), r1 = wld(WA_all, 1), r2 = wld(WA_all, 2), r3 = wld(WA_all, 3);
        short4v r4 = wld(WA_all, 4), r5 = wld(WA_all, 5), r6 = wld(WA_all, 6),
                r7 = wld(WA_all, 7), r8 = wld(WA_all, 8);
        wst(0, r0); wst(1, r1); wst(2, r2); wst(3, r3);
        wst(4, r4); wst(5, r5); wst(6, r6); wst(7, r7); wst(8, r8);
        __syncthreads();
    }

    for (int l_ = 0; l_ < NLAYERS; ++l_) {
        dil_cur = 1 << (l_ % 10);
        const int dnext = (l_ < NLAYERS - 1) ? (1 << ((l_ + 1) % 10)) : 0;
        const int thr = dnext + 32;
        const u16* WAn = WA_all + (size_t)(l_ + 1) * 9 * 4096;
        const u16* W2 = W2_all + (size_t)l_ * 2 * 4096;
        const float* bd = bd_all + l_ * 128;
        const float* bs = bs_all + l_ * 64;
        const float* br = br_all + l_ * 64;

        wait_nb(flagP, (unsigned)(l_ + 1));
        asm volatile("buffer_inv" ::: "memory");

        float4v acc[4];
#pragma unroll
        for (int mb = 0; mb < 4; ++mb) acc[mb] = (float4v)0.f;

        // ---- main GEMM: 9 chunks of K=32, wave owns 64 out-ch, depth-3 prefetch
        short8 p0, p1, p2;
        issue_bfrag(0, p0);
        issue_bfrag(1, p1);
        issue_bfrag(2, p2);
#pragma unroll
        for (int cc = 0; cc < 9; ++cc) {
            short8 bh;
            if ((cc % 3) == 0)      { bh = p0; if (cc + 3 < 9) issue_bfrag(cc + 3, p0); }
            else if ((cc % 3) == 1) { bh = p1; if (cc + 3 < 9) issue_bfrag(cc + 3, p1); }
            else                    { bh = p2; if (cc + 3 < 9) issue_bfrag(cc + 3, p2); }
            const char* cbuf = (const char*)wa_sm + cc * 8192;
#pragma unroll
            for (int mb = 0; mb < 4; ++mb) {
                short8 ah = *(const short8*)(cbuf + (chw * 4 + mb) * 1024 + l * 16);
                acc[mb] = __builtin_amdgcn_mfma_f32_16x16x32_bf16(ah, bh, acc[mb], 0, 0, 0);
            }
        }
        __syncthreads();                         // done reading wa_sm + h taps
        if (tid == 0) st_ag(rdP + (size_t)g * 32, (unsigned)(l_ + 1));

        // ---- residual h_in prefetch (chw=1 waves only)
        short4v ehq[4];
        if (chw) {
            int t = n0 + lr;
#pragma unroll
            for (int m = 0; m < 4; ++m) {
                size_t off = ((size_t)b * T_LEN + t) * 64 + m * 16 + lg * 4;
                ehq[m] = *(const short4v*)(hih + off);
            }
        }

        // ---- g-exchange: write bias-added pre-activations (bf16) to tg zone
#pragma unroll
        for (int mb = 0; mb < 4; ++mb) {
            int ch0 = (chw * 4 + mb) * 16 + lg * 4;
            const float4v bda = *(const float4v*)(bd + ch0);
            short4v gv;
#pragma unroll
            for (int r = 0; r < 4; ++r)
                gv[r] = (short)rne_bf16(acc[mb][r] + bda[r]);
            unsigned byteoff = (unsigned)(lr * 256 + ch0 * 2) ^ ((unsigned)(lr & 15) << 3);
            *(short4v*)(zg + byteoff) = gv;
        }
        __syncthreads();

        // ---- stage NEXT layer chunks 4-8 (issue loads, hide under z compute)
        short4v r4, r5, r6, r7, r8;
        if (l_ != NLAYERS - 1) {
            r4 = wld(WAn, 4); r5 = wld(WAn, 5); r6 = wld(WAn, 6);
            r7 = wld(WAn, 7); r8 = wld(WAn, 8);
        }

        // ---- z compute in registers: thread builds its two 2nd-GEMM B-frags
        short8 b2[2];
#pragma unroll
        for (int c2 = 0; c2 < 2; ++c2) {
#pragma unroll
            for (int j = 0; j < 8; ++j) {
                int ch = c2 * 32 + lg * 8 + j;
                unsigned offA = (unsigned)(lr * 256 + ch * 2) ^ ((unsigned)(lr & 15) << 3);
                unsigned offB = (unsigned)(lr * 256 + (ch + 64) * 2) ^ ((unsigned)(lr & 15) << 3);
                float xa = bf16_to_f32(*(const u16*)(zg + offA));
                float xb = bf16_to_f32(*(const u16*)(zg + offB));
                float e2 = __expf(2.f * xa);
                float th = 1.f - 2.f * __builtin_amdgcn_rcpf(e2 + 1.f);
                float sg = __builtin_amdgcn_rcpf(1.f + __expf(-xb));
                b2[c2][j] = (short)rne_bf16(th * sg);
            }
        }
        if (l_ != NLAYERS - 1) {
            wst(4, r4); wst(5, r5); wst(6, r6); wst(7, r7); wst(8, r8);
        }

        // ---- second GEMM: K=64, wave owns 64 out-ch, W2 from L2
        float4v acc2[4];
#pragma unroll
        for (int mb = 0; mb < 4; ++mb) acc2[mb] = (float4v)0.f;

#pragma unroll
        for (int c2 = 0; c2 < 2; ++c2) {
#pragma unroll
            for (int mb = 0; mb < 4; ++mb) {
                short8 ah = *(const short8*)(W2 + (size_t)c2 * 4096 + (chw * 4 + mb) * 512 + l * 8);
                acc2[mb] = __builtin_amdgcn_mfma_f32_16x16x32_bf16(ah, b2[c2], acc2[mb], 0, 0, 0);
            }
        }

        // ---- anti-dependency: neighbors done reading h^(l-1) before overwrite
        if (l_ != NLAYERS - 1) wait_nb(rdP, (unsigned)l_);

        // ---- epilogue: chw=0 -> skip accumulation; chw=1 -> residual h out
        if (chw == 0) {
#pragma unroll
            for (int mb = 0; mb < 4; ++mb) {
                int ch0 = mb * 16 + lg * 4;
                const float4v bsv = *(const float4v*)(bs + ch0);
                skipacc[mb] = skipacc[mb] + acc2[mb] + bsv;
            }
        } else if (l_ != NLAYERS - 1) {
#pragma unroll
            for (int mb = 0; mb < 4; ++mb) {
                int ch0 = mb * 16 + lg * 4;
                const float4v brv = *(const float4v*)(br + ch0);
                int t = n0 + lr;
                size_t off = ((size_t)b * T_LEN + t) * 64 + ch0;
                short4v hv = ehq[mb];
                short4v ohv;
#pragma unroll
                for (int r = 0; r < 4; ++r) {
                    float hr = bf16_to_f32((u16)hv[r]);
                    float xo = (acc2[mb][r] + brv[r] + hr) * SQRT_HALF;
                    ohv[r] = (short)rne_bf16(xo);
                }
                *(short4v*)(hoh + off) = ohv;
                if ((t - lkT <= thr) || (rkT - t <= thr))
                    st_sys(moh + off, __builtin_bit_cast(u64t, ohv));
            }
        }

        if (l_ != NLAYERS - 1) {
            __syncthreads();                     // h writes drained, g zones consumed
            if (tid == 0) st_ag(flagP + (size_t)g * 32, (unsigned)(l_ + 2));
            short4v q0 = wld(WAn, 0), q1 = wld(WAn, 1), q2 = wld(WAn, 2), q3 = wld(WAn, 3);
            wst(0, q0); wst(1, q1); wst(2, q2); wst(3, q3);
            __syncthreads();
        }
        u16* t1;
        t1 = hih; hih = hoh; hoh = t1;
        t1 = mih; mih = moh; moh = t1;
    }

    // ---- fused final head: skips (chw=0 regs) -> LDS -> relu/GEMV/relu/GEMV
    __syncthreads();
    char* sk = (char*)wa_sm;
    if (chw == 0) {
#pragma unroll
        for (int mb = 0; mb < 4; ++mb) {
            int tloc = tg * 16 + lr;
            int ch0 = mb * 16 + lg * 4;
            unsigned off = (unsigned)((tloc * 64 + ch0) * 4) ^ ((unsigned)(tloc & 7) << 5);
            *(float4v*)(sk + off) = skipacc[mb];
        }
    }
    float* w1s = (float*)((char*)wa_sm + 32768);
    for (int e = tid; e < 4096; e += 1024) w1s[e] = Wl1[e];
    __syncthreads();
    if (tid < 128) {
        int tloc = tid;
        float s[64];
#pragma unroll
        for (int i4 = 0; i4 < 16; ++i4) {
            unsigned off = (unsigned)((tloc * 64 + i4 * 4) * 4) ^ ((unsigned)(tloc & 7) << 5);
            float4v v = *(const float4v*)(sk + off);
#pragma unroll
            for (int r = 0; r < 4; ++r) s[i4 * 4 + r] = fmaxf(v[r] * C30, 0.f);
        }
        float acc = bl2[0];
        for (int o = 0; o < 64; ++o) {
            float a = bl1[o];
#pragma unroll
            for (int i = 0; i < 64; ++i) a = fmaf(w1s[o * 64 + i], s[i], a);
            acc = fmaf(Wl2[o], fmaxf(a, 0.f), acc);
        }
        y[(size_t)b * T_LEN + t0blk + tloc] = acc;
    }
}

// ---------------- launch ----------------
extern "C" void kernel_launch(void* const* d_in, const int* in_sizes, int n_in,
                              void* d_out, int out_size, void* d_ws, size_t ws_size,
                              hipStream_t stream)
{
    const float* x       = (const float*)d_in[0];
    const float* c       = (const float*)d_in[1];
    const float* W_first = (const float*)d_in[2];
    const float* b_first = (const float*)d_in[3];
    const float* W_cin   = (const float*)d_in[4];
    const float* W_up    = (const float*)d_in[5];
    const float* Wd      = (const float*)d_in[6];
    const float* bd      = (const float*)d_in[7];
    const float* Wa      = (const float*)d_in[8];
    const float* Ws      = (const float*)d_in[9];
    const float* bs      = (const float*)d_in[10];
    const float* Wr      = (const float*)d_in[11];
    const float* br      = (const float*)d_in[12];
    const float* Wl1     = (const float*)d_in[13];
    const float* bl1     = (const float*)d_in[14];
    const float* Wl2     = (const float*)d_in[15];
    const float* bl2     = (const float*)d_in[16];

    char* base = (char*)d_ws;
    size_t off = 0;
    auto alloc = [&](size_t bytes) { char* p = base + off; off += (bytes + 255) & ~(size_t)255; return p; };

    const size_t HSZ = (size_t)2 * T_LEN * 64 * 2;
    u16* cup  = (u16*)alloc((size_t)2 * T_LEN * 96 * 2);
    u16* h0   = (u16*)alloc(HSZ);
    u16* h1   = (u16*)alloc(HSZ);
    u16* m0   = (u16*)alloc(HSZ);
    u16* m1   = (u16*)alloc(HSZ);
    unsigned* bar    = (unsigned*)alloc(33792 * 4);
    unsigned* xcdmap = (unsigned*)alloc(4096);
    char* S = alloc(7200000);
    float* c1 = (float*)(S);
    float* u1 = (float*)(S + 81920);
    float* u2 = (float*)(S + 409600);
    float* u3 = (float*)(S + 1720320);
    u16* WA = (u16*)(S);
    u16* W2 = (u16*)(S + 2211840);

    cin_kernel<<<(2 * 128 * 80 + 255) / 256, 256, 0, stream>>>(c, W_cin, c1);
    up_kernel<<<(2 * 512 * 80 + 255) / 256, 256, 0, stream>>>(c1, u1, W_up + 0, 128);
    up_kernel<<<(2 * 2048 * 80 + 255) / 256, 256, 0, stream>>>(u1, u2, W_up + 9, 512);
    up_kernel<<<(2 * 8192 * 80 + 255) / 256, 256, 0, stream>>>(u2, u3, W_up + 18, 2048);
    upfinal_kernel<<<(2 * T_LEN * 96 + 255) / 256, 256, 0, stream>>>(u3, W_up + 27, cup);

    prep_wmain<<<(NLAYERS * 9 * 8 * 64 + 255) / 256, 256, 0, stream>>>(Wd, Wa, WA);
    prep_wsr<<<(NLAYERS * 2 * 8 * 64 + 255) / 256, 256, 0, stream>>>(Ws, Wr, W2);
    bar_init<<<64, 256, 0, stream>>>(bar);

    wavenet_kernel<<<NBLK, 1024, 0, stream>>>(
        x, W_first, b_first,
        h0, h1, m0, m1,
        cup, WA, W2,
        bd, bs, br, Wl1, bl1, Wl2, bl2,
        (float*)d_out, bar, xcdmap);
}

// Round 19
// 535.971 us; speedup vs baseline: 2.3677x; 2.3677x over previous
//
#include <hip/hip_runtime.h>
#include <math.h>

#define T_LEN 32768
#define NLAYERS 30
#define NBLK 512
#define SQRT_HALF 0.70710678118654752f
#define C30 0.18257418583505537f

typedef short short8 __attribute__((ext_vector_type(8)));
typedef short short4v __attribute__((ext_vector_type(4)));
typedef float float4v __attribute__((ext_vector_type(4)));
typedef unsigned short u16;
typedef unsigned long long u64t;
typedef u64t u64x2 __attribute__((ext_vector_type(2)));

__device__ inline u16 rne_bf16(float f){
    unsigned u = __builtin_bit_cast(unsigned, f);
    u += 0x7fffu + ((u >> 16) & 1u);
    return (u16)(u >> 16);
}
__device__ inline float bf16_to_f32(u16 h){
    unsigned u = ((unsigned)h) << 16;
    return __builtin_bit_cast(float, u);
}

// system-scope (sc0 sc1) accesses for cross-XCD mirror buffers
__device__ inline u64t ld_sys(const u16* p){
    return __hip_atomic_load((const u64t*)p, __ATOMIC_RELAXED, __HIP_MEMORY_SCOPE_SYSTEM);
}
__device__ inline void st_sys(u16* p, u64t v){
    __hip_atomic_store((u64t*)p, v, __ATOMIC_RELAXED, __HIP_MEMORY_SCOPE_SYSTEM);
}
__device__ inline unsigned ld_sys32(const unsigned* p){
    return __hip_atomic_load(p, __ATOMIC_RELAXED, __HIP_MEMORY_SCOPE_SYSTEM);
}
__device__ inline void st_sys32(unsigned* p, unsigned v){
    __hip_atomic_store(p, v, __ATOMIC_RELAXED, __HIP_MEMORY_SCOPE_SYSTEM);
}
__device__ inline unsigned ld_ag(const unsigned* p){
    return __hip_atomic_load(p, __ATOMIC_RELAXED, __HIP_MEMORY_SCOPE_AGENT);
}
__device__ inline void st_ag(unsigned* p, unsigned v){
    __hip_atomic_store(p, v, __ATOMIC_RELAXED, __HIP_MEMORY_SCOPE_AGENT);
}

// ---------------- weight prep: single-plane bf16 chunks (8KB each) ----------------
__global__ void prep_wmain(const float* __restrict__ Wd, const float* __restrict__ Wa,
                           u16* __restrict__ WA)
{
    int idx = blockIdx.x * 256 + threadIdx.x;
    if (idx >= NLAYERS * 9 * 8 * 64) return;
    int lane = idx & 63;
    int mb = (idx >> 6) & 7;
    int cc = (idx >> 9) % 9;
    int l_ = (idx >> 9) / 9;
    int m = mb * 16 + (lane & 15);
    int kbase = cc * 32 + (lane >> 4) * 8;
    size_t base = ((size_t)(l_ * 9 + cc)) * 4096 + mb * 512 + lane * 8;
#pragma unroll
    for (int j = 0; j < 8; ++j) {
        int k = kbase + j;
        float v = 0.f;
        if (k < 192) {
            int tap = k >> 6, i = k & 63;
            v = Wd[((size_t)(l_ * 128 + m) * 64 + i) * 3 + tap];
        } else if (k < 272) {
            v = Wa[(size_t)(l_ * 128 + m) * 80 + (k - 192)];
        }
        WA[base + j] = rne_bf16(v);
    }
}

__global__ void prep_wsr(const float* __restrict__ Ws, const float* __restrict__ Wr,
                         u16* __restrict__ W2)
{
    int idx = blockIdx.x * 256 + threadIdx.x;
    if (idx >= NLAYERS * 2 * 8 * 64) return;
    int lane = idx & 63;
    int mb = (idx >> 6) & 7;
    int cc = (idx >> 9) & 1;
    int l_ = idx >> 10;
    int m2 = mb * 16 + (lane & 15);
    int kbase = cc * 32 + (lane >> 4) * 8;
    size_t base = ((size_t)(l_ * 2 + cc)) * 4096 + mb * 512 + lane * 8;
#pragma unroll
    for (int j = 0; j < 8; ++j) {
        int k2 = kbase + j;
        float v = (m2 < 64) ? Ws[(size_t)(l_ * 64 + m2) * 64 + k2]
                            : Wr[(size_t)(l_ * 64 + (m2 - 64)) * 64 + k2];
        W2[base + j] = rne_bf16(v);
    }
}

// ---------------- upsampler (t-major) ----------------
__global__ void cin_kernel(const float* __restrict__ c, const float* __restrict__ Wcin,
                           float* __restrict__ c1)
{
    int idx = blockIdx.x * 256 + threadIdx.x;
    if (idx >= 2 * 128 * 80) return;
    int o = idx % 80;
    int f = (idx / 80) & 127;
    int b = idx / (80 * 128);
    float acc = 0.f;
    for (int ch = 0; ch < 80; ++ch)
        acc = fmaf(Wcin[o * 80 + ch], c[(b * 80 + ch) * 128 + f], acc);
    c1[idx] = acc;
}

__global__ void up_kernel(const float* __restrict__ in, float* __restrict__ out,
                          const float* __restrict__ w9, int Win)
{
    int idx = blockIdx.x * 256 + threadIdx.x;
    int Wout = Win * 4;
    int total = 2 * Wout * 80;
    if (idx >= total) return;
    int a = idx % 80;
    int t = (idx / 80) % Wout;
    int b = idx / (80 * Wout);
    const float* ip = in + (size_t)b * Win * 80 + a;
    float acc = 0.f;
#pragma unroll
    for (int j = 0; j < 9; ++j) {
        int q = t + j - 4;
        if (q >= 0 && q < Wout) acc = fmaf(w9[j], ip[(size_t)(q >> 2) * 80], acc);
    }
    out[idx] = acc;
}

__global__ void upfinal_kernel(const float* __restrict__ u3, const float* __restrict__ w9,
                               u16* __restrict__ cup)
{
    int idx = blockIdx.x * 256 + threadIdx.x;
    if (idx >= 2 * T_LEN * 96) return;
    int a = idx % 96;
    int t = (idx / 96) & (T_LEN - 1);
    int b = idx / (96 * T_LEN);
    float acc = 0.f;
    if (a < 80) {
        const float* ip = u3 + (size_t)b * 8192 * 80 + a;
#pragma unroll
        for (int j = 0; j < 9; ++j) {
            int q = t + j - 4;
            if (q >= 0 && q < T_LEN) acc = fmaf(w9[j], ip[(size_t)(q >> 2) * 80], acc);
        }
    }
    cup[idx] = rne_bf16(acc);
}

__global__ void bar_init(unsigned* bar){
    int i = blockIdx.x * 256 + threadIdx.x;
    for (int e = i; e < 33792; e += 256 * 64) bar[e] = 0u;
}

// ---------------- persistent fused WaveNet (neighbor dataflow sync) ----------------
// 512 blocks x 512 threads; h/z/cup single-plane bf16; hoisted per-tap
// address+mirror precompute (VALU cut vs round-17).
__global__ __launch_bounds__(512, 4) void wavenet_kernel(
    const float* __restrict__ x, const float* __restrict__ Wf, const float* __restrict__ bf,
    u16* __restrict__ h0, u16* __restrict__ h1,
    u16* __restrict__ m0, u16* __restrict__ m1,
    const u16* __restrict__ cup,
    const u16* __restrict__ WA_all, const u16* __restrict__ W2_all,
    const float* __restrict__ bd_all, const float* __restrict__ bs_all,
    const float* __restrict__ br_all,
    const float* __restrict__ Wl1, const float* __restrict__ bl1,
    const float* __restrict__ Wl2, const float* __restrict__ bl2,
    float* __restrict__ y, unsigned* __restrict__ bar, unsigned* __restrict__ xcdmap)
{
    __shared__ u16 wa_sm[36864];                // 72 KB: 9 chunks x 8KB (z + head alias it)
    const int tid = threadIdx.x;
    const int l  = tid & 63;
    const int w  = tid >> 6;                    // 0..7
    const int lr = l & 15;
    const int lg = l >> 4;
    const int bx = blockIdx.x;
    const int g  = ((bx & 7) << 6) | (bx >> 3);
    const int b  = g >> 8;
    const int gt = g & 255;
    const int t0blk = gt * 128;
    const int n0 = t0blk + w * 16;
    char* zb = (char*)wa_sm + w * 4096;

    unsigned* flagP = bar + 1024;               // p[512] @ 32-u32 spacing
    unsigned* rdP   = bar + 1024 + 16384;       // rd[512]

    int dil_cur = 1;
    // per-layer per-tap precompute (updated each layer)
    long toff[3];            // element offset of (b, n0+offd, ch0) in h/mirror
    unsigned tmir = 0;       // bit t: tap t uses mirror path

    auto grid_bar = [&](int k){
        __syncthreads();
        if (tid == 0) {
            const unsigned epoch = (unsigned)(k + 1);
            const int grp = bx & 7;
            unsigned* arr  = bar + grp * 32;
            unsigned* root = bar + 8 * 32;
            unsigned* rel  = bar + 9 * 32 + grp * 32;
            unsigned old = __hip_atomic_fetch_add(arr, 1u, __ATOMIC_RELAXED, __HIP_MEMORY_SCOPE_AGENT);
            if (old == epoch * 64u - 1u) {
                unsigned ro = __hip_atomic_fetch_add(root, 1u, __ATOMIC_RELAXED, __HIP_MEMORY_SCOPE_AGENT);
                if (ro == epoch * 8u - 1u) {
#pragma unroll
                    for (int j = 0; j < 8; ++j)
                        __hip_atomic_store(bar + 9 * 32 + j * 32, epoch, __ATOMIC_RELAXED, __HIP_MEMORY_SCOPE_AGENT);
                }
            }
            while (__hip_atomic_load(rel, __ATOMIC_RELAXED, __HIP_MEMORY_SCOPE_AGENT) < epoch)
                __builtin_amdgcn_s_sleep(16);
        }
        __syncthreads();
        asm volatile("buffer_inv" ::: "memory");
    };

    auto wait_nb = [&](const unsigned* fl, unsigned tgt){
        if (tid < 9 && tid != 4) {
            int jt = gt - 4 + tid;
            if (jt >= 0 && jt < 256) {
                const unsigned* fp = fl + (size_t)(b * 256 + jt) * 32;
                while (ld_ag(fp) < tgt) __builtin_amdgcn_s_sleep(4);
            }
        }
        __syncthreads();
    };

    auto wld = [&](const u16* Wg, int c){ return *(const short8*)(Wg + (size_t)c * 4096 + tid * 8); };
    auto wst = [&](int c, short8 v){ *(short8*)((char*)wa_sm + c * 8192 + tid * 16) = v; };

    // ---- publish tile->XCD map, build foreign mask
    unsigned myxcd;
    asm volatile("s_getreg_b32 %0, hwreg(HW_REG_XCC_ID)" : "=s"(myxcd));
    if (tid == 0) st_sys32(xcdmap + g, myxcd);
    grid_bar(0);

    unsigned fmask = 0;
    for (int i = 0; i < 11; ++i) {
        int j = gt - 5 + i;
        if (i != 5 && j >= 0 && j < 256) {
            unsigned xv = ld_sys32(xcdmap + b * 256 + j);
            if (xv != myxcd) fmask |= 1u << i;
        }
    }
    int lkT = -1000000, rkT = 1000000;
    for (int i = 4; i >= 0; --i) if ((fmask >> i) & 1) { lkT = t0blk + 128 * (i - 4) - 1; break; }
    for (int i = 6; i <= 10; ++i) if ((fmask >> i) & 1) { rkT = t0blk + 128 * (i - 5); break; }

    u16* hih = h0;
    u16* hoh = h1;
    u16* mih = m0;
    u16* moh = m1;
    const short8 zero8 = (short8)0;

    // per-layer tap precompute: toff[tap], tmir
    auto prep_taps = [&](){
        tmir = 0;
#pragma unroll
        for (int tap = 0; tap < 3; ++tap) {
            int offd = (tap - 1) * dil_cur;
            toff[tap] = ((long)b * T_LEN + n0 + offd) * 64;
            int ws0 = n0 + offd;
            int a0 = ws0 < 0 ? 0 : ws0;
            int a1 = (ws0 + 15 >= T_LEN) ? (T_LEN - 1) : (ws0 + 15);
            if (a0 <= a1) {
                int i_0 = (a0 >> 7) - gt + 5;
                int i_1 = (a1 >> 7) - gt + 5;
                if (((fmask >> i_0) & 1) || ((fmask >> i_1) & 1)) tmir |= 1u << tap;
            }
        }
    };

    // conv-tap b-frag: hoisted address; per-lane bounds check only
    auto issue_bfrag = [&](int cc, short8& BH){
        if (cc < 6) {
            const int tap = cc >> 1;
            const int i0 = (cc & 1) * 32 + lg * 8;
            int t = n0 + lr + (tap - 1) * dil_cur;
            if ((unsigned)t < (unsigned)T_LEN) {
                long off = toff[tap] + lr * 64 + i0;
                if ((tmir >> tap) & 1) {
                    u64x2 qh;
                    qh.x = ld_sys(mih + off); qh.y = ld_sys(mih + off + 4);
                    BH = __builtin_bit_cast(short8, qh);
                } else {
                    BH = *(const short8*)(hih + off);
                }
            } else { BH = zero8; }
        } else {
            const int a0 = (cc - 6) * 32 + lg * 8;
            int t = n0 + lr;
            BH = *(const short8*)(cup + ((size_t)b * T_LEN + t) * 96 + a0);
        }
    };

    // ---- fused first conv (cached single-plane + hi mirror, thr = d0+32 = 33)
#pragma unroll
    for (int e = 0; e < 4; ++e) {
        int q = e * 512 + tid;
        int tl = q >> 4, ch0 = (q & 15) * 4;
        int t = t0blk + tl;
        size_t bt = (size_t)b * T_LEN + t;
        float xv = x[bt];
        short4v hv4;
#pragma unroll
        for (int r = 0; r < 4; ++r) {
            float v = fmaf(Wf[ch0 + r], xv, bf[ch0 + r]);
            hv4[r] = (short)rne_bf16(v);
        }
        *(short4v*)(h0 + bt * 64 + ch0) = hv4;
        if ((t - lkT <= 33) || (rkT - t <= 33))
            st_sys(m0 + bt * 64 + ch0, __builtin_bit_cast(u64t, hv4));
    }

    float4v skipacc[4];
#pragma unroll
    for (int mb = 0; mb < 4; ++mb) skipacc[mb] = (float4v)0.f;

    // h^(0) published
    __syncthreads();
    if (tid == 0) st_ag(flagP + (size_t)g * 32, 1u);

    // stage layer-0 weights
    {
        short8 r0 = wld(WA_all, 0), r1 = wld(WA_all, 1), r2 = wld(WA_all, 2), r3 = wld(WA_all, 3);
        short8 r4 = wld(WA_all, 4), r5 = wld(WA_all, 5), r6 = wld(WA_all, 6),
               r7 = wld(WA_all, 7), r8 = wld(WA_all, 8);
        wst(0, r0); wst(1, r1); wst(2, r2); wst(3, r3);
        wst(4, r4); wst(5, r5); wst(6, r6); wst(7, r7); wst(8, r8);
        __syncthreads();
    }

    for (int l_ = 0; l_ < NLAYERS; ++l_) {
        dil_cur = 1 << (l_ % 10);
        const int dnext = (l_ < NLAYERS - 1) ? (1 << ((l_ + 1) % 10)) : 0;
        const int thr = dnext + 32;
        const u16* WAn = WA_all + (size_t)(l_ + 1) * 9 * 4096;
        const u16* W2 = W2_all + (size_t)l_ * 2 * 4096;
        const float* bd = bd_all + l_ * 128;
        const float* bs = bs_all + l_ * 64;
        const float* br = br_all + l_ * 64;

        prep_taps();
        wait_nb(flagP, (unsigned)(l_ + 1));
        asm volatile("buffer_inv" ::: "memory");

        float4v acc[8];
#pragma unroll
        for (int mb = 0; mb < 8; ++mb) acc[mb] = (float4v)0.f;

        // ---- main GEMM: 9 chunks of K=32, 1 MFMA/frag, depth-3 prefetch
        short8 p0, p1, p2;
        issue_bfrag(0, p0);
        issue_bfrag(1, p1);
        issue_bfrag(2, p2);
#pragma unroll
        for (int cc = 0; cc < 9; ++cc) {
            short8 bh;
            if ((cc % 3) == 0)      { bh = p0; if (cc + 3 < 9) issue_bfrag(cc + 3, p0); }
            else if ((cc % 3) == 1) { bh = p1; if (cc + 3 < 9) issue_bfrag(cc + 3, p1); }
            else                    { bh = p2; if (cc + 3 < 9) issue_bfrag(cc + 3, p2); }
            const char* cbuf = (const char*)wa_sm + cc * 8192;
#pragma unroll
            for (int mb = 0; mb < 8; ++mb) {
                short8 ah = *(const short8*)(cbuf + mb * 1024 + l * 16);
                acc[mb] = __builtin_amdgcn_mfma_f32_16x16x32_bf16(ah, bh, acc[mb], 0, 0, 0);
            }
        }
        __syncthreads();                         // all waves done reading wa_sm + h taps
        if (tid == 0) st_ag(rdP + (size_t)g * 32, (unsigned)(l_ + 1));

        // ---- residual h_in prefetch (own tile, single plane)
        short4v ehq[4];
        {
            int t = n0 + lr;
#pragma unroll
            for (int m = 0; m < 4; ++m) {
                size_t off = ((size_t)b * T_LEN + t) * 64 + m * 16 + lg * 4;
                ehq[m] = *(const short4v*)(hih + off);
            }
        }

        // ---- gating -> per-wave z zone (single plane, 2KB)
#pragma unroll
        for (int mb = 0; mb < 4; ++mb) {
            const float4v bda = *(const float4v*)(bd + mb * 16 + lg * 4);
            const float4v bdb = *(const float4v*)(bd + 64 + mb * 16 + lg * 4);
            int t = lr;
            short4v zhv;
#pragma unroll
            for (int r = 0; r < 4; ++r) {
                float xa = acc[mb][r] + bda[r];
                float xb = acc[mb + 4][r] + bdb[r];
                float e2 = __expf(2.f * xa);
                float th = 1.f - 2.f * __builtin_amdgcn_rcpf(e2 + 1.f);
                float sg = __builtin_amdgcn_rcpf(1.f + __expf(-xb));
                zhv[r] = (short)rne_bf16(th * sg);
            }
            unsigned byteoff = (unsigned)((t * 64 + mb * 16 + lg * 4) * 2) ^ ((unsigned)(t & 7) << 4);
            *(short4v*)(zb + byteoff) = zhv;
        }

        // ---- stage NEXT layer chunks 4-8 (region dead after post-GEMM sync)
        if (l_ != NLAYERS - 1) {
            short8 r4 = wld(WAn, 4), r5 = wld(WAn, 5), r6 = wld(WAn, 6),
                   r7 = wld(WAn, 7), r8 = wld(WAn, 8);
            wst(4, r4); wst(5, r5); wst(6, r6); wst(7, r7); wst(8, r8);
        }

        // ---- second GEMM: K=64, z single-plane
        float4v acc2[8];
#pragma unroll
        for (int mb = 0; mb < 8; ++mb) acc2[mb] = (float4v)0.f;

#pragma unroll
        for (int c2 = 0; c2 < 2; ++c2) {
            int t = lr;
            unsigned k0 = (unsigned)(c2 * 32 + lg * 8);
            unsigned byteoff = (unsigned)((t * 64 + k0) * 2) ^ ((unsigned)(t & 7) << 4);
            short8 b2h = *(const short8*)(zb + byteoff);
#pragma unroll
            for (int mb = 0; mb < 8; ++mb) {
                short8 ah = *(const short8*)(W2 + (size_t)c2 * 4096 + mb * 512 + l * 8);
                acc2[mb] = __builtin_amdgcn_mfma_f32_16x16x32_bf16(ah, b2h, acc2[mb], 0, 0, 0);
            }
        }

        // ---- anti-dependency: neighbors done reading h^(l-1) before overwrite
        if (l_ != NLAYERS - 1) wait_nb(rdP, (unsigned)l_);

        // ---- epilogue
#pragma unroll
        for (int mb = 0; mb < 8; ++mb) {
            int ch0 = (mb & 3) * 16 + lg * 4;
            if (mb < 4) {
                const float4v bsv = *(const float4v*)(bs + ch0);
                skipacc[mb] = skipacc[mb] + acc2[mb] + bsv;
            } else if (l_ != NLAYERS - 1) {
                const float4v brv = *(const float4v*)(br + ch0);
                int t = n0 + lr;
                size_t off = ((size_t)b * T_LEN + t) * 64 + ch0;
                short4v hv = ehq[mb - 4];
                short4v ohv;
#pragma unroll
                for (int r = 0; r < 4; ++r) {
                    float hr = bf16_to_f32((u16)hv[r]);
                    float xo = (acc2[mb][r] + brv[r] + hr) * SQRT_HALF;
                    ohv[r] = (short)rne_bf16(xo);
                }
                *(short4v*)(hoh + off) = ohv;
                if ((t - lkT <= thr) || (rkT - t <= thr))
                    st_sys(moh + off, __builtin_bit_cast(u64t, ohv));
            }
        }

        if (l_ != NLAYERS - 1) {
            __syncthreads();                     // h writes drained, z consumed
            if (tid == 0) st_ag(flagP + (size_t)g * 32, (unsigned)(l_ + 2));
            short8 r0 = wld(WAn, 0), r1 = wld(WAn, 1), r2 = wld(WAn, 2), r3 = wld(WAn, 3);
            wst(0, r0); wst(1, r1); wst(2, r2); wst(3, r3);
            __syncthreads();
        }
        u16* t1;
        t1 = hih; hih = hoh; hoh = t1;
        t1 = mih; mih = moh; moh = t1;
    }

    // ---- fused final head: skips (regs) -> LDS -> relu/GEMV/relu/GEMV
    __syncthreads();
    char* sk = (char*)wa_sm;
#pragma unroll
    for (int mb = 0; mb < 4; ++mb) {
        int tloc = w * 16 + lr;
        int ch0 = mb * 16 + lg * 4;
        unsigned off = (unsigned)((tloc * 64 + ch0) * 4) ^ ((unsigned)(tloc & 7) << 5);
        *(float4v*)(sk + off) = skipacc[mb];
    }
    float* w1s = (float*)((char*)wa_sm + 32768);
    for (int e = tid; e < 4096; e += 512) w1s[e] = Wl1[e];
    __syncthreads();
    if (tid < 128) {
        int tloc = tid;
        float s[64];
#pragma unroll
        for (int i4 = 0; i4 < 16; ++i4) {
            unsigned off = (unsigned)((tloc * 64 + i4 * 4) * 4) ^ ((unsigned)(tloc & 7) << 5);
            float4v v = *(const float4v*)(sk + off);
#pragma unroll
            for (int r = 0; r < 4; ++r) s[i4 * 4 + r] = fmaxf(v[r] * C30, 0.f);
        }
        float acc = bl2[0];
        for (int o = 0; o < 64; ++o) {
            float a = bl1[o];
#pragma unroll
            for (int i = 0; i < 64; ++i) a = fmaf(w1s[o * 64 + i], s[i], a);
            acc = fmaf(Wl2[o], fmaxf(a, 0.f), acc);
        }
        y[(size_t)b * T_LEN + t0blk + tloc] = acc;
    }
}

// ---------------- launch ----------------
extern "C" void kernel_launch(void* const* d_in, const int* in_sizes, int n_in,
                              void* d_out, int out_size, void* d_ws, size_t ws_size,
                              hipStream_t stream)
{
    const float* x       = (const float*)d_in[0];
    const float* c       = (const float*)d_in[1];
    const float* W_first = (const float*)d_in[2];
    const float* b_first = (const float*)d_in[3];
    const float* W_cin   = (const float*)d_in[4];
    const float* W_up    = (const float*)d_in[5];
    const float* Wd      = (const float*)d_in[6];
    const float* bd      = (const float*)d_in[7];
    const float* Wa      = (const float*)d_in[8];
    const float* Ws      = (const float*)d_in[9];
    const float* bs      = (const float*)d_in[10];
    const float* Wr      = (const float*)d_in[11];
    const float* br      = (const float*)d_in[12];
    const float* Wl1     = (const float*)d_in[13];
    const float* bl1     = (const float*)d_in[14];
    const float* Wl2     = (const float*)d_in[15];
    const float* bl2     = (const float*)d_in[16];

    char* base = (char*)d_ws;
    size_t off = 0;
    auto alloc = [&](size_t bytes) { char* p = base + off; off += (bytes + 255) & ~(size_t)255; return p; };

    const size_t HSZ = (size_t)2 * T_LEN * 64 * 2;
    u16* cup  = (u16*)alloc((size_t)2 * T_LEN * 96 * 2);
    u16* h0   = (u16*)alloc(HSZ);
    u16* h1   = (u16*)alloc(HSZ);
    u16* m0   = (u16*)alloc(HSZ);
    u16* m1   = (u16*)alloc(HSZ);
    unsigned* bar    = (unsigned*)alloc(33792 * 4);
    unsigned* xcdmap = (unsigned*)alloc(4096);
    char* S = alloc(7200000);
    float* c1 = (float*)(S);
    float* u1 = (float*)(S + 81920);
    float* u2 = (float*)(S + 409600);
    float* u3 = (float*)(S + 1720320);
    u16* WA = (u16*)(S);
    u16* W2 = (u16*)(S + 2211840);

    cin_kernel<<<(2 * 128 * 80 + 255) / 256, 256, 0, stream>>>(c, W_cin, c1);
    up_kernel<<<(2 * 512 * 80 + 255) / 256, 256, 0, stream>>>(c1, u1, W_up + 0, 128);
    up_kernel<<<(2 * 2048 * 80 + 255) / 256, 256, 0, stream>>>(u1, u2, W_up + 9, 512);
    up_kernel<<<(2 * 8192 * 80 + 255) / 256, 256, 0, stream>>>(u2, u3, W_up + 18, 2048);
    upfinal_kernel<<<(2 * T_LEN * 96 + 255) / 256, 256, 0, stream>>>(u3, W_up + 27, cup);

    prep_wmain<<<(NLAYERS * 9 * 8 * 64 + 255) / 256, 256, 0, stream>>>(Wd, Wa, WA);
    prep_wsr<<<(NLAYERS * 2 * 8 * 64 + 255) / 256, 256, 0, stream>>>(Ws, Wr, W2);
    bar_init<<<64, 256, 0, stream>>>(bar);

    wavenet_kernel<<<NBLK, 512, 0, stream>>>(
        x, W_first, b_first,
        h0, h1, m0, m1,
        cup, WA, W2,
        bd, bs, br, Wl1, bl1, Wl2, bl2,
        (float*)d_out, bar, xcdmap);
}

// Round 20
// 525.754 us; speedup vs baseline: 2.4137x; 1.0194x over previous
//
#include <hip/hip_runtime.h>
#include <math.h>

#define T_LEN 32768
#define NLAYERS 30
#define NBLK 512
#define SQRT_HALF 0.70710678118654752f
#define C30 0.18257418583505537f

typedef short short8 __attribute__((ext_vector_type(8)));
typedef short short4v __attribute__((ext_vector_type(4)));
typedef float float4v __attribute__((ext_vector_type(4)));
typedef unsigned short u16;
typedef unsigned long long u64t;
typedef u64t u64x2 __attribute__((ext_vector_type(2)));

__device__ inline u16 rne_bf16(float f){
    unsigned u = __builtin_bit_cast(unsigned, f);
    u += 0x7fffu + ((u >> 16) & 1u);
    return (u16)(u >> 16);
}
__device__ inline float bf16_to_f32(u16 h){
    unsigned u = ((unsigned)h) << 16;
    return __builtin_bit_cast(float, u);
}

// system-scope (sc0 sc1) accesses for cross-XCD mirror buffers
__device__ inline u64t ld_sys(const u16* p){
    return __hip_atomic_load((const u64t*)p, __ATOMIC_RELAXED, __HIP_MEMORY_SCOPE_SYSTEM);
}
__device__ inline void st_sys(u16* p, u64t v){
    __hip_atomic_store((u64t*)p, v, __ATOMIC_RELAXED, __HIP_MEMORY_SCOPE_SYSTEM);
}
__device__ inline unsigned ld_sys32(const unsigned* p){
    return __hip_atomic_load(p, __ATOMIC_RELAXED, __HIP_MEMORY_SCOPE_SYSTEM);
}
__device__ inline void st_sys32(unsigned* p, unsigned v){
    __hip_atomic_store(p, v, __ATOMIC_RELAXED, __HIP_MEMORY_SCOPE_SYSTEM);
}
__device__ inline unsigned ld_ag(const unsigned* p){
    return __hip_atomic_load(p, __ATOMIC_RELAXED, __HIP_MEMORY_SCOPE_AGENT);
}
__device__ inline void st_ag(unsigned* p, unsigned v){
    __hip_atomic_store(p, v, __ATOMIC_RELAXED, __HIP_MEMORY_SCOPE_AGENT);
}

// ---------------- weight prep: single-plane bf16 chunks (8KB each) ----------------
__global__ void prep_wmain(const float* __restrict__ Wd, const float* __restrict__ Wa,
                           u16* __restrict__ WA)
{
    int idx = blockIdx.x * 256 + threadIdx.x;
    if (idx >= NLAYERS * 9 * 8 * 64) return;
    int lane = idx & 63;
    int mb = (idx >> 6) & 7;
    int cc = (idx >> 9) % 9;
    int l_ = (idx >> 9) / 9;
    int m = mb * 16 + (lane & 15);
    int kbase = cc * 32 + (lane >> 4) * 8;
    size_t base = ((size_t)(l_ * 9 + cc)) * 4096 + mb * 512 + lane * 8;
#pragma unroll
    for (int j = 0; j < 8; ++j) {
        int k = kbase + j;
        float v = 0.f;
        if (k < 192) {
            int tap = k >> 6, i = k & 63;
            v = Wd[((size_t)(l_ * 128 + m) * 64 + i) * 3 + tap];
        } else if (k < 272) {
            v = Wa[(size_t)(l_ * 128 + m) * 80 + (k - 192)];
        }
        WA[base + j] = rne_bf16(v);
    }
}

__global__ void prep_wsr(const float* __restrict__ Ws, const float* __restrict__ Wr,
                         u16* __restrict__ W2)
{
    int idx = blockIdx.x * 256 + threadIdx.x;
    if (idx >= NLAYERS * 2 * 8 * 64) return;
    int lane = idx & 63;
    int mb = (idx >> 6) & 7;
    int cc = (idx >> 9) & 1;
    int l_ = idx >> 10;
    int m2 = mb * 16 + (lane & 15);
    int kbase = cc * 32 + (lane >> 4) * 8;
    size_t base = ((size_t)(l_ * 2 + cc)) * 4096 + mb * 512 + lane * 8;
#pragma unroll
    for (int j = 0; j < 8; ++j) {
        int k2 = kbase + j;
        float v = (m2 < 64) ? Ws[(size_t)(l_ * 64 + m2) * 64 + k2]
                            : Wr[(size_t)(l_ * 64 + (m2 - 64)) * 64 + k2];
        W2[base + j] = rne_bf16(v);
    }
}

// ---------------- upsampler (t-major) ----------------
__global__ void cin_kernel(const float* __restrict__ c, const float* __restrict__ Wcin,
                           float* __restrict__ c1)
{
    int idx = blockIdx.x * 256 + threadIdx.x;
    if (idx >= 2 * 128 * 80) return;
    int o = idx % 80;
    int f = (idx / 80) & 127;
    int b = idx / (80 * 128);
    float acc = 0.f;
    for (int ch = 0; ch < 80; ++ch)
        acc = fmaf(Wcin[o * 80 + ch], c[(b * 80 + ch) * 128 + f], acc);
    c1[idx] = acc;
}

__global__ void up_kernel(const float* __restrict__ in, float* __restrict__ out,
                          const float* __restrict__ w9, int Win)
{
    int idx = blockIdx.x * 256 + threadIdx.x;
    int Wout = Win * 4;
    int total = 2 * Wout * 80;
    if (idx >= total) return;
    int a = idx % 80;
    int t = (idx / 80) % Wout;
    int b = idx / (80 * Wout);
    const float* ip = in + (size_t)b * Win * 80 + a;
    float acc = 0.f;
#pragma unroll
    for (int j = 0; j < 9; ++j) {
        int q = t + j - 4;
        if (q >= 0 && q < Wout) acc = fmaf(w9[j], ip[(size_t)(q >> 2) * 80], acc);
    }
    out[idx] = acc;
}

__global__ void upfinal_kernel(const float* __restrict__ u3, const float* __restrict__ w9,
                               u16* __restrict__ cup)
{
    int idx = blockIdx.x * 256 + threadIdx.x;
    if (idx >= 2 * T_LEN * 96) return;
    int a = idx % 96;
    int t = (idx / 96) & (T_LEN - 1);
    int b = idx / (96 * T_LEN);
    float acc = 0.f;
    if (a < 80) {
        const float* ip = u3 + (size_t)b * 8192 * 80 + a;
#pragma unroll
        for (int j = 0; j < 9; ++j) {
            int q = t + j - 4;
            if (q >= 0 && q < T_LEN) acc = fmaf(w9[j], ip[(size_t)(q >> 2) * 80], acc);
        }
    }
    cup[idx] = rne_bf16(acc);
}

__global__ void bar_init(unsigned* bar){
    int i = blockIdx.x * 256 + threadIdx.x;
    for (int e = i; e < 33792; e += 256 * 64) bar[e] = 0u;
}

// ---------------- persistent fused WaveNet (neighbor dataflow sync) ----------------
// 512 blocks x 512 threads; h/z/cup single-plane bf16; rdP anti-dep removed
// (implied by flagP wait: flag l+1 publishes only after neighbor's layer-(l-1)
// epilogue, which contains all its h^(l-1) reads); single-rcp gating.
__global__ __launch_bounds__(512, 4) void wavenet_kernel(
    const float* __restrict__ x, const float* __restrict__ Wf, const float* __restrict__ bf,
    u16* __restrict__ h0, u16* __restrict__ h1,
    u16* __restrict__ m0, u16* __restrict__ m1,
    const u16* __restrict__ cup,
    const u16* __restrict__ WA_all, const u16* __restrict__ W2_all,
    const float* __restrict__ bd_all, const float* __restrict__ bs_all,
    const float* __restrict__ br_all,
    const float* __restrict__ Wl1, const float* __restrict__ bl1,
    const float* __restrict__ Wl2, const float* __restrict__ bl2,
    float* __restrict__ y, unsigned* __restrict__ bar, unsigned* __restrict__ xcdmap)
{
    __shared__ u16 wa_sm[36864];                // 72 KB: 9 chunks x 8KB (z + head alias it)
    const int tid = threadIdx.x;
    const int l  = tid & 63;
    const int w  = tid >> 6;                    // 0..7
    const int lr = l & 15;
    const int lg = l >> 4;
    const int bx = blockIdx.x;
    const int g  = ((bx & 7) << 6) | (bx >> 3);
    const int b  = g >> 8;
    const int gt = g & 255;
    const int t0blk = gt * 128;
    const int n0 = t0blk + w * 16;
    char* zb = (char*)wa_sm + w * 4096;

    unsigned* flagP = bar + 1024;               // p[512] @ 32-u32 spacing

    int dil_cur = 1;
    long toff[3];
    unsigned tmir = 0;

    auto grid_bar = [&](int k){
        __syncthreads();
        if (tid == 0) {
            const unsigned epoch = (unsigned)(k + 1);
            const int grp = bx & 7;
            unsigned* arr  = bar + grp * 32;
            unsigned* root = bar + 8 * 32;
            unsigned* rel  = bar + 9 * 32 + grp * 32;
            unsigned old = __hip_atomic_fetch_add(arr, 1u, __ATOMIC_RELAXED, __HIP_MEMORY_SCOPE_AGENT);
            if (old == epoch * 64u - 1u) {
                unsigned ro = __hip_atomic_fetch_add(root, 1u, __ATOMIC_RELAXED, __HIP_MEMORY_SCOPE_AGENT);
                if (ro == epoch * 8u - 1u) {
#pragma unroll
                    for (int j = 0; j < 8; ++j)
                        __hip_atomic_store(bar + 9 * 32 + j * 32, epoch, __ATOMIC_RELAXED, __HIP_MEMORY_SCOPE_AGENT);
                }
            }
            while (__hip_atomic_load(rel, __ATOMIC_RELAXED, __HIP_MEMORY_SCOPE_AGENT) < epoch)
                __builtin_amdgcn_s_sleep(16);
        }
        __syncthreads();
        asm volatile("buffer_inv" ::: "memory");
    };

    auto wait_nb = [&](const unsigned* fl, unsigned tgt){
        if (tid < 9 && tid != 4) {
            int jt = gt - 4 + tid;
            if (jt >= 0 && jt < 256) {
                const unsigned* fp = fl + (size_t)(b * 256 + jt) * 32;
                while (ld_ag(fp) < tgt) __builtin_amdgcn_s_sleep(4);
            }
        }
        __syncthreads();
    };

    auto wld = [&](const u16* Wg, int c){ return *(const short8*)(Wg + (size_t)c * 4096 + tid * 8); };
    auto wst = [&](int c, short8 v){ *(short8*)((char*)wa_sm + c * 8192 + tid * 16) = v; };

    // ---- publish tile->XCD map, build foreign mask
    unsigned myxcd;
    asm volatile("s_getreg_b32 %0, hwreg(HW_REG_XCC_ID)" : "=s"(myxcd));
    if (tid == 0) st_sys32(xcdmap + g, myxcd);
    grid_bar(0);

    unsigned fmask = 0;
    for (int i = 0; i < 11; ++i) {
        int j = gt - 5 + i;
        if (i != 5 && j >= 0 && j < 256) {
            unsigned xv = ld_sys32(xcdmap + b * 256 + j);
            if (xv != myxcd) fmask |= 1u << i;
        }
    }
    int lkT = -1000000, rkT = 1000000;
    for (int i = 4; i >= 0; --i) if ((fmask >> i) & 1) { lkT = t0blk + 128 * (i - 4) - 1; break; }
    for (int i = 6; i <= 10; ++i) if ((fmask >> i) & 1) { rkT = t0blk + 128 * (i - 5); break; }

    u16* hih = h0;
    u16* hoh = h1;
    u16* mih = m0;
    u16* moh = m1;
    const short8 zero8 = (short8)0;

    auto prep_taps = [&](){
        tmir = 0;
#pragma unroll
        for (int tap = 0; tap < 3; ++tap) {
            int offd = (tap - 1) * dil_cur;
            toff[tap] = ((long)b * T_LEN + n0 + offd) * 64;
            int ws0 = n0 + offd;
            int a0 = ws0 < 0 ? 0 : ws0;
            int a1 = (ws0 + 15 >= T_LEN) ? (T_LEN - 1) : (ws0 + 15);
            if (a0 <= a1) {
                int i_0 = (a0 >> 7) - gt + 5;
                int i_1 = (a1 >> 7) - gt + 5;
                if (((fmask >> i_0) & 1) || ((fmask >> i_1) & 1)) tmir |= 1u << tap;
            }
        }
    };

    auto issue_bfrag = [&](int cc, short8& BH){
        if (cc < 6) {
            const int tap = cc >> 1;
            const int i0 = (cc & 1) * 32 + lg * 8;
            int t = n0 + lr + (tap - 1) * dil_cur;
            if ((unsigned)t < (unsigned)T_LEN) {
                long off = toff[tap] + lr * 64 + i0;
                if ((tmir >> tap) & 1) {
                    u64x2 qh;
                    qh.x = ld_sys(mih + off); qh.y = ld_sys(mih + off + 4);
                    BH = __builtin_bit_cast(short8, qh);
                } else {
                    BH = *(const short8*)(hih + off);
                }
            } else { BH = zero8; }
        } else {
            const int a0 = (cc - 6) * 32 + lg * 8;
            int t = n0 + lr;
            BH = *(const short8*)(cup + ((size_t)b * T_LEN + t) * 96 + a0);
        }
    };

    // ---- fused first conv (cached single-plane + hi mirror, thr = d0+32 = 33)
#pragma unroll
    for (int e = 0; e < 4; ++e) {
        int q = e * 512 + tid;
        int tl = q >> 4, ch0 = (q & 15) * 4;
        int t = t0blk + tl;
        size_t bt = (size_t)b * T_LEN + t;
        float xv = x[bt];
        short4v hv4;
#pragma unroll
        for (int r = 0; r < 4; ++r) {
            float v = fmaf(Wf[ch0 + r], xv, bf[ch0 + r]);
            hv4[r] = (short)rne_bf16(v);
        }
        *(short4v*)(h0 + bt * 64 + ch0) = hv4;
        if ((t - lkT <= 33) || (rkT - t <= 33))
            st_sys(m0 + bt * 64 + ch0, __builtin_bit_cast(u64t, hv4));
    }

    float4v skipacc[4];
#pragma unroll
    for (int mb = 0; mb < 4; ++mb) skipacc[mb] = (float4v)0.f;

    // h^(0) published
    __syncthreads();
    if (tid == 0) st_ag(flagP + (size_t)g * 32, 1u);

    // stage layer-0 weights
    {
        short8 r0 = wld(WA_all, 0), r1 = wld(WA_all, 1), r2 = wld(WA_all, 2), r3 = wld(WA_all, 3);
        short8 r4 = wld(WA_all, 4), r5 = wld(WA_all, 5), r6 = wld(WA_all, 6),
               r7 = wld(WA_all, 7), r8 = wld(WA_all, 8);
        wst(0, r0); wst(1, r1); wst(2, r2); wst(3, r3);
        wst(4, r4); wst(5, r5); wst(6, r6); wst(7, r7); wst(8, r8);
        __syncthreads();
    }

    for (int l_ = 0; l_ < NLAYERS; ++l_) {
        dil_cur = 1 << (l_ % 10);
        const int dnext = (l_ < NLAYERS - 1) ? (1 << ((l_ + 1) % 10)) : 0;
        const int thr = dnext + 32;
        const u16* WAn = WA_all + (size_t)(l_ + 1) * 9 * 4096;
        const u16* W2 = W2_all + (size_t)l_ * 2 * 4096;
        const float* bd = bd_all + l_ * 128;
        const float* bs = bs_all + l_ * 64;
        const float* br = br_all + l_ * 64;

        prep_taps();
        // waiting for p[nb] >= l_+1 also guarantees nb finished ALL reads of
        // h^(l_-1) (its layer-(l_-1) epilogue precedes that publish), so the
        // ping-pong overwrite in our epilogue needs no separate rd flag.
        wait_nb(flagP, (unsigned)(l_ + 1));
        asm volatile("buffer_inv" ::: "memory");

        float4v acc[8];
#pragma unroll
        for (int mb = 0; mb < 8; ++mb) acc[mb] = (float4v)0.f;

        // ---- main GEMM: 9 chunks of K=32, 1 MFMA/frag, depth-3 prefetch
        short8 p0, p1, p2;
        issue_bfrag(0, p0);
        issue_bfrag(1, p1);
        issue_bfrag(2, p2);
#pragma unroll
        for (int cc = 0; cc < 9; ++cc) {
            short8 bh;
            if ((cc % 3) == 0)      { bh = p0; if (cc + 3 < 9) issue_bfrag(cc + 3, p0); }
            else if ((cc % 3) == 1) { bh = p1; if (cc + 3 < 9) issue_bfrag(cc + 3, p1); }
            else                    { bh = p2; if (cc + 3 < 9) issue_bfrag(cc + 3, p2); }
            const char* cbuf = (const char*)wa_sm + cc * 8192;
#pragma unroll
            for (int mb = 0; mb < 8; ++mb) {
                short8 ah = *(const short8*)(cbuf + mb * 1024 + l * 16);
                acc[mb] = __builtin_amdgcn_mfma_f32_16x16x32_bf16(ah, bh, acc[mb], 0, 0, 0);
            }
        }
        __syncthreads();                         // all waves done reading wa_sm + h taps

        // ---- residual h_in prefetch (own tile, single plane)
        short4v ehq[4];
        {
            int t = n0 + lr;
#pragma unroll
            for (int m = 0; m < 4; ++m) {
                size_t off = ((size_t)b * T_LEN + t) * 64 + m * 16 + lg * 4;
                ehq[m] = *(const short4v*)(hih + off);
            }
        }

        // ---- gating -> per-wave z zone (single plane, 2KB); single-rcp form:
        // z = (e2-1) / ((e2+1)*(1+e3)), e2 = exp(2xa), e3 = exp(-xb)
#pragma unroll
        for (int mb = 0; mb < 4; ++mb) {
            const float4v bda = *(const float4v*)(bd + mb * 16 + lg * 4);
            const float4v bdb = *(const float4v*)(bd + 64 + mb * 16 + lg * 4);
            int t = lr;
            short4v zhv;
#pragma unroll
            for (int r = 0; r < 4; ++r) {
                float xa = acc[mb][r] + bda[r];
                float xb = acc[mb + 4][r] + bdb[r];
                float e2 = __expf(2.f * xa);
                float e3 = __expf(-xb);
                float tnum = e2 - 1.f;
                float tden = e2 + 1.f;
                float den = fmaf(tden, e3, tden);         // (e2+1)*(1+e3)
                float z = tnum * __builtin_amdgcn_rcpf(den);
                zhv[r] = (short)rne_bf16(z);
            }
            unsigned byteoff = (unsigned)((t * 64 + mb * 16 + lg * 4) * 2) ^ ((unsigned)(t & 7) << 4);
            *(short4v*)(zb + byteoff) = zhv;
        }

        // ---- stage NEXT layer chunks 4-8 (region dead after post-GEMM sync)
        if (l_ != NLAYERS - 1) {
            short8 r4 = wld(WAn, 4), r5 = wld(WAn, 5), r6 = wld(WAn, 6),
                   r7 = wld(WAn, 7), r8 = wld(WAn, 8);
            wst(4, r4); wst(5, r5); wst(6, r6); wst(7, r7); wst(8, r8);
        }

        // ---- second GEMM: K=64, z single-plane
        float4v acc2[8];
#pragma unroll
        for (int mb = 0; mb < 8; ++mb) acc2[mb] = (float4v)0.f;

#pragma unroll
        for (int c2 = 0; c2 < 2; ++c2) {
            int t = lr;
            unsigned k0 = (unsigned)(c2 * 32 + lg * 8);
            unsigned byteoff = (unsigned)((t * 64 + k0) * 2) ^ ((unsigned)(t & 7) << 4);
            short8 b2h = *(const short8*)(zb + byteoff);
#pragma unroll
            for (int mb = 0; mb < 8; ++mb) {
                short8 ah = *(const short8*)(W2 + (size_t)c2 * 4096 + mb * 512 + l * 8);
                acc2[mb] = __builtin_amdgcn_mfma_f32_16x16x32_bf16(ah, b2h, acc2[mb], 0, 0, 0);
            }
        }

        // ---- epilogue (anti-dep vs neighbors already implied by flagP wait)
#pragma unroll
        for (int mb = 0; mb < 8; ++mb) {
            int ch0 = (mb & 3) * 16 + lg * 4;
            if (mb < 4) {
                const float4v bsv = *(const float4v*)(bs + ch0);
                skipacc[mb] = skipacc[mb] + acc2[mb] + bsv;
            } else if (l_ != NLAYERS - 1) {
                const float4v brv = *(const float4v*)(br + ch0);
                int t = n0 + lr;
                size_t off = ((size_t)b * T_LEN + t) * 64 + ch0;
                short4v hv = ehq[mb - 4];
                short4v ohv;
#pragma unroll
                for (int r = 0; r < 4; ++r) {
                    float hr = bf16_to_f32((u16)hv[r]);
                    float xo = (acc2[mb][r] + brv[r] + hr) * SQRT_HALF;
                    ohv[r] = (short)rne_bf16(xo);
                }
                *(short4v*)(hoh + off) = ohv;
                if ((t - lkT <= thr) || (rkT - t <= thr))
                    st_sys(moh + off, __builtin_bit_cast(u64t, ohv));
            }
        }

        if (l_ != NLAYERS - 1) {
            __syncthreads();                     // h writes drained, z consumed
            if (tid == 0) st_ag(flagP + (size_t)g * 32, (unsigned)(l_ + 2));
            short8 r0 = wld(WAn, 0), r1 = wld(WAn, 1), r2 = wld(WAn, 2), r3 = wld(WAn, 3);
            wst(0, r0); wst(1, r1); wst(2, r2); wst(3, r3);
            __syncthreads();
        }
        u16* t1;
        t1 = hih; hih = hoh; hoh = t1;
        t1 = mih; mih = moh; moh = t1;
    }

    // ---- fused final head: skips (regs) -> LDS -> relu/GEMV/relu/GEMV
    __syncthreads();
    char* sk = (char*)wa_sm;
#pragma unroll
    for (int mb = 0; mb < 4; ++mb) {
        int tloc = w * 16 + lr;
        int ch0 = mb * 16 + lg * 4;
        unsigned off = (unsigned)((tloc * 64 + ch0) * 4) ^ ((unsigned)(tloc & 7) << 5);
        *(float4v*)(sk + off) = skipacc[mb];
    }
    float* w1s = (float*)((char*)wa_sm + 32768);
    for (int e = tid; e < 4096; e += 512) w1s[e] = Wl1[e];
    __syncthreads();
    if (tid < 128) {
        int tloc = tid;
        float s[64];
#pragma unroll
        for (int i4 = 0; i4 < 16; ++i4) {
            unsigned off = (unsigned)((tloc * 64 + i4 * 4) * 4) ^ ((unsigned)(tloc & 7) << 5);
            float4v v = *(const float4v*)(sk + off);
#pragma unroll
            for (int r = 0; r < 4; ++r) s[i4 * 4 + r] = fmaxf(v[r] * C30, 0.f);
        }
        float acc = bl2[0];
        for (int o = 0; o < 64; ++o) {
            float a = bl1[o];
#pragma unroll
            for (int i = 0; i < 64; ++i) a = fmaf(w1s[o * 64 + i], s[i], a);
            acc = fmaf(Wl2[o], fmaxf(a, 0.f), acc);
        }
        y[(size_t)b * T_LEN + t0blk + tloc] = acc;
    }
}

// ---------------- launch ----------------
extern "C" void kernel_launch(void* const* d_in, const int* in_sizes, int n_in,
                              void* d_out, int out_size, void* d_ws, size_t ws_size,
                              hipStream_t stream)
{
    const float* x       = (const float*)d_in[0];
    const float* c       = (const float*)d_in[1];
    const float* W_first = (const float*)d_in[2];
    const float* b_first = (const float*)d_in[3];
    const float* W_cin   = (const float*)d_in[4];
    const float* W_up    = (const float*)d_in[5];
    const float* Wd      = (const float*)d_in[6];
    const float* bd      = (const float*)d_in[7];
    const float* Wa      = (const float*)d_in[8];
    const float* Ws      = (const float*)d_in[9];
    const float* bs      = (const float*)d_in[10];
    const float* Wr      = (const float*)d_in[11];
    const float* br      = (const float*)d_in[12];
    const float* Wl1     = (const float*)d_in[13];
    const float* bl1     = (const float*)d_in[14];
    const float* Wl2     = (const float*)d_in[15];
    const float* bl2     = (const float*)d_in[16];

    char* base = (char*)d_ws;
    size_t off = 0;
    auto alloc = [&](size_t bytes) { char* p = base + off; off += (bytes + 255) & ~(size_t)255; return p; };

    const size_t HSZ = (size_t)2 * T_LEN * 64 * 2;
    u16* cup  = (u16*)alloc((size_t)2 * T_LEN * 96 * 2);
    u16* h0   = (u16*)alloc(HSZ);
    u16* h1   = (u16*)alloc(HSZ);
    u16* m0   = (u16*)alloc(HSZ);
    u16* m1   = (u16*)alloc(HSZ);
    unsigned* bar    = (unsigned*)alloc(33792 * 4);
    unsigned* xcdmap = (unsigned*)alloc(4096);
    char* S = alloc(7200000);
    float* c1 = (float*)(S);
    float* u1 = (float*)(S + 81920);
    float* u2 = (float*)(S + 409600);
    float* u3 = (float*)(S + 1720320);
    u16* WA = (u16*)(S);
    u16* W2 = (u16*)(S + 2211840);

    cin_kernel<<<(2 * 128 * 80 + 255) / 256, 256, 0, stream>>>(c, W_cin, c1);
    up_kernel<<<(2 * 512 * 80 + 255) / 256, 256, 0, stream>>>(c1, u1, W_up + 0, 128);
    up_kernel<<<(2 * 2048 * 80 + 255) / 256, 256, 0, stream>>>(u1, u2, W_up + 9, 512);
    up_kernel<<<(2 * 8192 * 80 + 255) / 256, 256, 0, stream>>>(u2, u3, W_up + 18, 2048);
    upfinal_kernel<<<(2 * T_LEN * 96 + 255) / 256, 256, 0, stream>>>(u3, W_up + 27, cup);

    prep_wmain<<<(NLAYERS * 9 * 8 * 64 + 255) / 256, 256, 0, stream>>>(Wd, Wa, WA);
    prep_wsr<<<(NLAYERS * 2 * 8 * 64 + 255) / 256, 256, 0, stream>>>(Ws, Wr, W2);
    bar_init<<<64, 256, 0, stream>>>(bar);

    wavenet_kernel<<<NBLK, 512, 0, stream>>>(
        x, W_first, b_first,
        h0, h1, m0, m1,
        cup, WA, W2,
        bd, bs, br, Wl1, bl1, Wl2, bl2,
        (float*)d_out, bar, xcdmap);
}